// Round 2
// baseline (578.381 us; speedup 1.0000x reference)
//
#include <hip/hip_runtime.h>
#include <stdint.h>

// ---------------------------------------------------------------------------
// QuantizedLinear: out[M,N] = x[M,K] @ dequant(Wpacked)[N,K]^T
//   M = B*S = 8192, K = 4096, N = O = 4096
// Prepass x(fp32)->bf16 and W(4-bit LUT, delivered as int32/elem)->bf16 into
// d_ws, then m97-style 128x128 bf16 MFMA GEMM (global_load_lds width 16).
// ---------------------------------------------------------------------------

typedef short short8 __attribute__((ext_vector_type(8)));   // 8 bf16 = 4 VGPR
typedef float floatx4 __attribute__((ext_vector_type(4)));  // MFMA acc

#define BM 128
#define BN 128
#define BK 32

// round-to-nearest-even fp32 -> bf16 (returned in low 16 bits)
__device__ __forceinline__ uint32_t f2bf(float f) {
  union { float f; uint32_t u; } v; v.f = f;
  return (v.u + 0x7FFFu + ((v.u >> 16) & 1u)) >> 16;
}

// async global->LDS, 16B per lane; LDS dest is wave-uniform base + lane*16
__device__ __forceinline__ void async_copy16(const void* g, void* l) {
  __builtin_amdgcn_global_load_lds(
      (const __attribute__((address_space(1))) uint32_t*)g,
      (__attribute__((address_space(3))) uint32_t*)l, 16, 0, 0);
}

// --------------------------- prepass: x -> bf16 ----------------------------
__global__ void cvt_x_kernel(const float4* __restrict__ x, uint2* __restrict__ xb, int n4) {
  int t = blockIdx.x * blockDim.x + threadIdx.x;
  if (t >= n4) return;
  float4 v = x[t];
  uint2 o;
  o.x = f2bf(v.x) | (f2bf(v.y) << 16);
  o.y = f2bf(v.z) | (f2bf(v.w) << 16);
  xb[t] = o;
}

// ------------------- prepass: 4-bit packed W -> bf16 [N,K] -----------------
// HARNESS NOTE: weight_packed (uint8 in the reference) arrives as int32 per
// element ("integer -> const int*"). One packed byte per int32, value 0..255.
// Byte at position p covers k=2p (HIGH nibble) and k=2p+1 (low nibble).
__global__ void dequant_kernel(const int* __restrict__ wp,
                               const float* __restrict__ cent,
                               const float* __restrict__ scales,
                               unsigned short* __restrict__ wb, int K) {
  __shared__ float lut[16];
  if (threadIdx.x < 16) lut[threadIdx.x] = cent[threadIdx.x];
  __syncthreads();
  int t = blockIdx.x * blockDim.x + threadIdx.x;  // one thread per 4 packed bytes
  const int epr = K >> 1;                          // int32 elements per row
  int o  = t / (epr >> 2);
  int j4 = t % (epr >> 2);
  const int4 pk = *(const int4*)(wp + (size_t)o * epr + j4 * 4);
  int kbase = j4 * 8;                              // 8 weights, one 64-block
  float s = scales[(size_t)o * (K >> 6) + (kbase >> 6)];
  unsigned b[4] = {(unsigned)pk.x & 0xFFu, (unsigned)pk.y & 0xFFu,
                   (unsigned)pk.z & 0xFFu, (unsigned)pk.w & 0xFFu};
  uint32_t w32[4];
#pragma unroll
  for (int i = 0; i < 4; ++i) {
    uint32_t hi = f2bf(lut[b[i] >> 4] * s);  // first element of the byte
    uint32_t lo = f2bf(lut[b[i] & 15] * s);  // second element
    w32[i] = hi | (lo << 16);
  }
  *(uint4*)(wb + (size_t)o * K + kbase) = make_uint4(w32[0], w32[1], w32[2], w32[3]);
}

// ------------------------------ main GEMM ----------------------------------
// A[M,K] bf16, B[N,K] bf16 (i.e. B^T layout), C[M,N] fp32. m97 structure.
__global__ __launch_bounds__(256) void gemm_bt(const unsigned short* __restrict__ A,
                                               const unsigned short* __restrict__ B,
                                               float* __restrict__ C,
                                               int M, int N, int K) {
  __shared__ unsigned short As[BM * BK];  // 8 KiB
  __shared__ unsigned short Bs[BN * BK];  // 8 KiB
  const int tid   = threadIdx.x;
  const int lane  = tid & 63;
  const int wave  = tid >> 6;
  const int waveM = wave >> 1;   // 2x2 wave grid, each wave does 64x64
  const int waveN = wave & 1;
  const int bm = blockIdx.y * BM;
  const int bn = blockIdx.x * BN;

  // staging: lane l of wave w covers tile row w*16 + (l>>2), cols (l&3)*8..+8
  const int srow = tid >> 2;
  const int scol = (tid & 3) * 8;
  const unsigned short* aptr0 = A + (size_t)(bm + srow) * K + scol;
  const unsigned short* aptr1 = A + (size_t)(bm + 64 + srow) * K + scol;
  const unsigned short* bptr0 = B + (size_t)(bn + srow) * K + scol;
  const unsigned short* bptr1 = B + (size_t)(bn + 64 + srow) * K + scol;
  char* ldsA = (char*)As + wave * 1024;   // wave-uniform LDS bases
  char* ldsB = (char*)Bs + wave * 1024;

  // fragment reads: lane l -> row (l&15), k-offset (l>>4)*8
  const int fr = lane & 15;
  const int fk = (lane >> 4) * 8;
  const short8* ar[4];
  const short8* br[4];
#pragma unroll
  for (int i = 0; i < 4; ++i) {
    ar[i] = (const short8*)(As + (waveM * 64 + i * 16 + fr) * BK + fk);
    br[i] = (const short8*)(Bs + (waveN * 64 + i * 16 + fr) * BK + fk);
  }

  floatx4 acc[4][4] = {};

  for (int kt = 0; kt < K; kt += BK) {
    __syncthreads();                         // protect LDS from overwrite
    async_copy16(aptr0 + kt, ldsA);
    async_copy16(aptr1 + kt, ldsA + 4096);
    async_copy16(bptr0 + kt, ldsB);
    async_copy16(bptr1 + kt, ldsB + 4096);
    __syncthreads();                         // compiler emits vmcnt(0) drain

    short8 af[4], bw[4];
#pragma unroll
    for (int i = 0; i < 4; ++i) { af[i] = *ar[i]; bw[i] = *br[i]; }
#pragma unroll
    for (int mi = 0; mi < 4; ++mi)
#pragma unroll
      for (int nj = 0; nj < 4; ++nj)
        acc[mi][nj] = __builtin_amdgcn_mfma_f32_16x16x32_bf16(af[mi], bw[nj], acc[mi][nj], 0, 0, 0);
  }

  // C/D layout: col = lane&15, row = (lane>>4)*4 + reg
  const int r0 = bm + waveM * 64 + (lane >> 4) * 4;
  const int c0 = bn + waveN * 64 + (lane & 15);
#pragma unroll
  for (int mi = 0; mi < 4; ++mi)
#pragma unroll
    for (int nj = 0; nj < 4; ++nj)
#pragma unroll
      for (int i = 0; i < 4; ++i)
        C[(size_t)(r0 + mi * 16 + i) * N + (c0 + nj * 16)] = acc[mi][nj][i];
}

// ------------------------- fallback (ws too small) -------------------------
__global__ void naive_kernel(const float* __restrict__ x, const int* __restrict__ wp,
                             const float* __restrict__ cent, const float* __restrict__ scales,
                             float* __restrict__ out, int M, int N, int K) {
  __shared__ float lut[16];
  if (threadIdx.x < 16) lut[threadIdx.x] = cent[threadIdx.x];
  __syncthreads();
  int n = blockIdx.x * blockDim.x + threadIdx.x;
  int m = blockIdx.y;
  if (n >= N || m >= M) return;
  const float* xr = x + (size_t)m * K;
  const int* wr = wp + (size_t)n * (K / 2);
  float acc = 0.f;
  for (int kb = 0; kb < K / 64; ++kb) {
    float s = scales[(size_t)n * (K / 64) + kb];
    float a = 0.f;
    for (int j = 0; j < 32; ++j) {
      unsigned b = (unsigned)wr[kb * 32 + j] & 0xFFu;
      a += xr[kb * 64 + 2 * j] * lut[b >> 4] + xr[kb * 64 + 2 * j + 1] * lut[b & 15];
    }
    acc += a * s;
  }
  out[(size_t)m * N + n] = acc;
}

// ------------------------------- launcher ----------------------------------
extern "C" void kernel_launch(void* const* d_in, const int* in_sizes, int n_in,
                              void* d_out, int out_size, void* d_ws, size_t ws_size,
                              hipStream_t stream) {
  const float* x      = (const float*)d_in[0];
  const int*   wp     = (const int*)d_in[1];
  const float* cent   = (const float*)d_in[2];
  const float* scales = (const float*)d_in[3];
  float*       out    = (float*)d_out;

  const int K = 4096;
  const int M = in_sizes[0] / K;                        // 8192
  const int O = (int)(((size_t)in_sizes[1] * 2) / K);   // 4096

  size_t need = (size_t)M * K * 2 + (size_t)O * K * 2;  // 96 MiB
  if (ws_size >= need) {
    unsigned short* xb = (unsigned short*)d_ws;
    unsigned short* wb = xb + (size_t)M * K;

    int n4 = M * K / 4;
    cvt_x_kernel<<<(n4 + 255) / 256, 256, 0, stream>>>((const float4*)x, (uint2*)xb, n4);

    int nt = O * (K / 8);  // one thread per 4 packed bytes
    dequant_kernel<<<(nt + 255) / 256, 256, 0, stream>>>(wp, cent, scales, wb, K);

    dim3 grid(O / BN, M / BM);  // (32, 64)
    gemm_bt<<<grid, 256, 0, stream>>>(xb, wb, out, M, O, K);
  } else {
    dim3 grid((O + 255) / 256, M);
    naive_kernel<<<grid, 256, 0, stream>>>(x, wp, cent, scales, out, M, O, K);
  }
}